// Round 11
// baseline (302.504 us; speedup 1.0000x reference)
//
#include <hip/hip_runtime.h>
#include <hip/hip_bf16.h>

typedef unsigned char  u8;
typedef unsigned short u16;
typedef unsigned int   u32;
typedef __attribute__((ext_vector_type(8)))  short bf16x8;
typedef __attribute__((ext_vector_type(4)))  float f32x4;
typedef __attribute__((ext_vector_type(4)))  int   i32x4;
typedef __attribute__((ext_vector_type(16))) int   i32x16;
typedef __attribute__((ext_vector_type(4)))  u16   u16x4;

__device__ __forceinline__ u16 f2bf(float f) {
  union { float f; u32 u; } v; v.f = f;
  u32 r = v.u + 0x7FFFu + ((v.u >> 16) & 1u);   // RNE
  return (u16)(r >> 16);
}
__device__ __forceinline__ int q127(float x) { return (int)rintf(x * 127.0f); }

#define GLL16(gptr, lptr)                                                            \
  __builtin_amdgcn_global_load_lds((const __attribute__((address_space(1))) u32*)(gptr), \
                                   (__attribute__((address_space(3))) u32*)(lptr), 16, 0, 0)

// lgkm-only barrier: does NOT drain vmcnt, so global prefetches stay in flight
#define BARRIER_LGKM() do { asm volatile("s_waitcnt lgkmcnt(0)" ::: "memory"); \
                            __builtin_amdgcn_s_barrier(); } while (0)

// ---------------------------------------------------------------- f32 -> bf16
__global__ __launch_bounds__(256) void cvt_bf16(const float* __restrict__ in,
                                                u16* __restrict__ out, int n4) {
  int i = blockIdx.x * blockDim.x + threadIdx.x;
  int stride = gridDim.x * blockDim.x;
  for (; i < n4; i += stride) {
    float4 v = ((const float4*)in)[i];
    u16x4 o = { f2bf(v.x), f2bf(v.y), f2bf(v.z), f2bf(v.w) };
    ((u16x4*)out)[i] = o;
  }
}

// ------------- keys [16384][768] f32 -> Ki8, layout [d16=48][key=16384][16B] i8
__global__ __launch_bounds__(256) void buildK(const float* __restrict__ in,
                                              u8* __restrict__ out) {
  __shared__ float tile[64][65];
  int kt = blockIdx.x;            // 64 keys per block
  int t = threadIdx.x;
  int r0 = t >> 6, c = t & 63;
  for (int dc = 0; dc < 12; ++dc) {
    if (dc) __syncthreads();
#pragma unroll
    for (int i = 0; i < 16; ++i) {
      int r = i * 4 + r0;
      tile[r][c] = in[(size_t)(kt * 64 + r) * 768 + dc * 64 + c];
    }
    __syncthreads();
    int d16l = t >> 6, key = t & 63;   // d16l in 0..3
    u32 wd[4];
#pragma unroll
    for (int g = 0; g < 4; ++g) {
      u32 v = 0;
#pragma unroll
      for (int j = 0; j < 4; ++j)
        v |= (u32)(q127(tile[key][d16l * 16 + g * 4 + j]) & 255) << (8 * j);
      wd[g] = v;
    }
    uint4 val = { wd[0], wd[1], wd[2], wd[3] };
    *(uint4*)(out + ((size_t)(dc * 4 + d16l) * 16384 + (size_t)(kt * 64 + key)) * 16) = val;
  }
}

// ------------- values [16384][768] f32 -> Vi8, layout [k16=1024][d=768][16B] i8
__global__ __launch_bounds__(256) void buildV(const float* __restrict__ in,
                                              u8* __restrict__ out) {
  __shared__ float tile[64][65];
  int kt = blockIdx.x;            // 64 keys per block
  int t = threadIdx.x;
  int r0 = t >> 6, c = t & 63;
  for (int dc = 0; dc < 12; ++dc) {
    if (dc) __syncthreads();
#pragma unroll
    for (int i = 0; i < 16; ++i) {
      int r = i * 4 + r0;
      tile[r][c] = in[(size_t)(kt * 64 + r) * 768 + dc * 64 + c];
    }
    __syncthreads();
    int k16l = t >> 6, dl = t & 63;    // k16l in 0..3
    u32 wd[4];
#pragma unroll
    for (int g = 0; g < 4; ++g) {
      u32 v = 0;
#pragma unroll
      for (int j = 0; j < 4; ++j)
        v |= (u32)(q127(tile[k16l * 16 + g * 4 + j][dl]) & 255) << (8 * j);
      wd[g] = v;
    }
    uint4 val = { wd[0], wd[1], wd[2], wd[3] };
    *(uint4*)(out + ((size_t)(kt * 4 + k16l) * 768 + (size_t)(dc * 64 + dl)) * 16) = val;
  }
}

// ---------------------------------------------------------------- GEMM1 (bf16)
__global__ __launch_bounds__(256) void gemm1(const u16* __restrict__ A,
                                             const u16* __restrict__ B,
                                             const float* __restrict__ bias,
                                             float* __restrict__ C) {
  __shared__ u16 As[2][128 * 32];
  __shared__ u16 Bs[2][128 * 32];
  int t = threadIdx.x;
  int brow = blockIdx.x * 128, bcol = blockIdx.y * 128;
  int w = t >> 6, l = t & 63;
  int l15 = l & 15, l4 = l >> 4;
  int wr = (w >> 1) * 64, wc = (w & 1) * 64;
  f32x4 acc[4][4];
#pragma unroll
  for (int i = 0; i < 4; ++i)
#pragma unroll
    for (int j = 0; j < 4; ++j) acc[i][j] = f32x4{0.f, 0.f, 0.f, 0.f};

  auto stage = [&](int buf, int kt) {
#pragma unroll
    for (int i = 0; i < 2; ++i) {
      int id = t + i * 256;
      int row = id >> 2, c = id & 3;
      int cs = (c ^ (row & 3)) * 8;
      GLL16(A + (size_t)(brow + row) * 1024 + kt * 32 + cs, &As[buf][id * 8]);
      GLL16(B + (size_t)(bcol + row) * 1024 + kt * 32 + cs, &Bs[buf][id * 8]);
    }
  };
  stage(0, 0);
  for (int kt = 0; kt < 32; ++kt) {
    int buf = kt & 1;
    __syncthreads();
    if (kt < 31) stage(buf ^ 1, kt + 1);
    bf16x8 a[4], b[4];
#pragma unroll
    for (int mf = 0; mf < 4; ++mf) {
      int row = wr + mf * 16 + l15;
      a[mf] = *(const bf16x8*)&As[buf][row * 32 + ((l4 ^ (row & 3)) * 8)];
    }
#pragma unroll
    for (int nf = 0; nf < 4; ++nf) {
      int row = wc + nf * 16 + l15;
      b[nf] = *(const bf16x8*)&Bs[buf][row * 32 + ((l4 ^ (row & 3)) * 8)];
    }
#pragma unroll
    for (int mf = 0; mf < 4; ++mf)
#pragma unroll
      for (int nf = 0; nf < 4; ++nf)
        acc[mf][nf] = __builtin_amdgcn_mfma_f32_16x16x32_bf16(a[mf], b[nf], acc[mf][nf], 0, 0, 0);
  }
#pragma unroll
  for (int mf = 0; mf < 4; ++mf)
#pragma unroll
    for (int nf = 0; nf < 4; ++nf) {
      int col = bcol + wc + nf * 16 + l15;
      float bv = bias[col];
#pragma unroll
      for (int j = 0; j < 4; ++j) {
        int row = brow + wr + mf * 16 + l4 * 4 + j;
        C[(size_t)row * 768 + col] = acc[mf][nf][j] + bv;
      }
    }
}

// ---------------------------------------------------------------- row L2-normalize -> i8
__global__ __launch_bounds__(384) void rownorm8(const float* __restrict__ P,
                                                u8* __restrict__ q8) {
  int row = blockIdx.x, t = threadIdx.x;
  size_t base = (size_t)row * 768;
  float2 v = *(const float2*)&P[base + 2 * t];
  float ss = v.x * v.x + v.y * v.y;
#pragma unroll
  for (int o = 32; o; o >>= 1) ss += __shfl_xor(ss, o);
  __shared__ float wsum[6];
  if ((t & 63) == 0) wsum[t >> 6] = ss;
  __syncthreads();
  float tot = wsum[0] + wsum[1] + wsum[2] + wsum[3] + wsum[4] + wsum[5];
  float inv = 1.0f / fmaxf(sqrtf(tot), 1e-12f);
  int a = q127(v.x * inv), b = q127(v.y * inv);
  *(u16*)(q8 + base + 2 * t) = (u16)((a & 255) | ((b & 255) << 8));
}

// ---------------------------------------------------------------- fused attention, i8
// Round-11 = round-10 + lagged-PV reorder (T15 analog): PV(it-1) runs between
// QK(it) and exp(it), so PV's MFMAs (independent of sacc) hide the QK retire
// latency and overlap exp's VALU burst. Buffer safety: PV(it-1) reads
// Ps[(it-1)&1] (visible since barrier it-1, drained by lgkm wait at barrier it);
// exp(it) writes Ps[it&1] — disjoint. Math identical to round 10.
__global__ __launch_bounds__(1024, 4) void attn(const u8* __restrict__ q8,
                                                const u8* __restrict__ Ki8,
                                                const u8* __restrict__ Vi8,
                                                const float* __restrict__ beta_p,
                                                u16* __restrict__ Opart,
                                                float* __restrict__ lpart) {
  __shared__ i32x4 Qlds[48 * 64];     // 48 KB [c16][q]
  __shared__ i32x4 Ps[2][32 * 64];    // 2 x 32 KB [kc16][q]
  __shared__ float lred[16][64];      // 4 KB
  int t = threadIdx.x;
  int w = t >> 6, l = t & 63;
  int ql = l & 31, hi = l >> 5;        // 32x32 lanes
  int l15 = l & 15, l4g = l >> 4;      // 16x16 lanes (0..3)
  int split = blockIdx.x, qb = blockIdx.y;
  int qrow0 = qb * 64;
  float beta = beta_p[0];
  float c1 = beta * 1.44269504089f / 16129.0f;          // int logit -> log2 domain
  float lg2ps = 6.98868468677f - beta * 1.44269504089f; // log2(127) - beta*log2(e)
  float invps = expf(beta) / 127.0f;                    // descale for lsum
  float ovs = expf(beta) / 16129.0f;                    // i32 PV acc -> float

  // ---- stage Q [64 q][768 d] i8 into [c16][q] (once)
#pragma unroll
  for (int i = 0; i < 3; ++i) {
    int id = i * 1024 + t;             // id = c16*64 + q
    int c16 = id >> 6, q = id & 63;
    Qlds[id] = *(const i32x4*)(q8 + (size_t)(qrow0 + q) * 768 + (size_t)c16 * 16);
  }

  i32x4 oacc[4][3];
#pragma unroll
  for (int mq = 0; mq < 4; ++mq)
#pragma unroll
    for (int nd = 0; nd < 3; ++nd) oacc[mq][nd] = i32x4{0, 0, 0, 0};
  int lsum0 = 0, lsum1 = 0;

  int kbase = split * 8192;
  const i32x4* Kp = (const i32x4*)Ki8 + (size_t)hi * 16384 + (size_t)(kbase + w * 32 + ql);
  const i32x4* Vp = (const i32x4*)Vi8 + ((size_t)(kbase >> 4) + l4g) * 768 + (size_t)(w * 48 + l15);

  // preload K tile 0 (3-step lookahead, in flight across the staging barrier)
  i32x4 kb[3];
#pragma unroll
  for (int s = 0; s < 3; ++s) kb[s] = Kp[(size_t)(2 * s) * 16384];

  i32x4 vb[2][3];   // rolling V buffer for the lagged PV

  __syncthreads();

  for (int it = 0; it < 16; ++it) {
    int n0 = it * 512;
    const i32x4* kp = Kp + n0;
    i32x4* psb = &Ps[it & 1][0];

    // ---------- QK^T(it): wave w -> keys [n0+w*32,+32), all 64 q; 24 steps of K=32
    i32x16 sacc0 = (i32x16)0;
    i32x16 sacc1 = (i32x16)0;
    __builtin_amdgcn_s_setprio(1);
#pragma unroll
    for (int ks = 0; ks < 24; ++ks) {
      i32x4 av = kb[ks % 3];
      if (ks < 21) kb[ks % 3] = kp[(size_t)(2 * (ks + 3)) * 16384];
      i32x4 q0 = Qlds[(2 * ks + hi) * 64 + ql];
      i32x4 q1 = Qlds[(2 * ks + hi) * 64 + ql + 32];
      sacc0 = __builtin_amdgcn_mfma_i32_32x32x32_i8(av, q0, sacc0, 0, 0, 0);
      sacc1 = __builtin_amdgcn_mfma_i32_32x32x32_i8(av, q1, sacc1, 0, 0, 0);
    }
    __builtin_amdgcn_s_setprio(0);

    // ---------- prefetch K for next tile (stays in flight across barrier)
    if (it < 15) {
      const i32x4* kpn = Kp + (size_t)(it + 1) * 512;
#pragma unroll
      for (int s = 0; s < 3; ++s) kb[s] = kpn[(size_t)(2 * s) * 16384];
    }

    // ---------- PV(it-1): lagged, independent of sacc -> overlaps exp(it) below
    if (it > 0) {
      int m0 = (it - 1) * 512;
      i32x4* psp = &Ps[(it - 1) & 1][0];
      __builtin_amdgcn_s_setprio(1);
#pragma unroll
      for (int ksv = 0; ksv < 8; ++ksv) {
        int cur = ksv & 1;
        if (ksv < 7) {
#pragma unroll
          for (int nd = 0; nd < 3; ++nd)
            vb[cur ^ 1][nd] = Vp[((size_t)(m0 >> 4) + (ksv + 1) * 4) * 768 + nd * 16];
        }
#pragma unroll
        for (int mq = 0; mq < 4; ++mq) {
          i32x4 pa = psp[(4 * ksv + l4g) * 64 + mq * 16 + l15];
          oacc[mq][0] = __builtin_amdgcn_mfma_i32_16x16x64_i8(pa, vb[cur][0], oacc[mq][0], 0, 0, 0);
          oacc[mq][1] = __builtin_amdgcn_mfma_i32_16x16x64_i8(pa, vb[cur][1], oacc[mq][1], 0, 0, 0);
          oacc[mq][2] = __builtin_amdgcn_mfma_i32_16x16x64_i8(pa, vb[cur][2], oacc[mq][2], 0, 0, 0);
        }
      }
      __builtin_amdgcn_s_setprio(0);
    }

    // ---------- exp(it) (pre-scaled), quantize P -> i8 -> Ps[it&1]; lsum via sdot4
    // sacc reg r: key-in-wave = (r&3) + 8*(r>>2) + 4*hi ; q = ql (+32 for sacc1)
#pragma unroll
    for (int qf = 0; qf < 2; ++qf) {
      int q = ql + qf * 32;
      int lacc = 0;
#pragma unroll
      for (int rg = 0; rg < 4; ++rg) {
        float p0, p1, p2, p3;
        if (qf == 0) {
          p0 = exp2f(fmaf(c1, (float)sacc0[rg * 4 + 0], lg2ps));
          p1 = exp2f(fmaf(c1, (float)sacc0[rg * 4 + 1], lg2ps));
          p2 = exp2f(fmaf(c1, (float)sacc0[rg * 4 + 2], lg2ps));
          p3 = exp2f(fmaf(c1, (float)sacc0[rg * 4 + 3], lg2ps));
        } else {
          p0 = exp2f(fmaf(c1, (float)sacc1[rg * 4 + 0], lg2ps));
          p1 = exp2f(fmaf(c1, (float)sacc1[rg * 4 + 1], lg2ps));
          p2 = exp2f(fmaf(c1, (float)sacc1[rg * 4 + 2], lg2ps));
          p3 = exp2f(fmaf(c1, (float)sacc1[rg * 4 + 3], lg2ps));
        }
        int i0 = (int)rintf(fminf(p0, 127.f));
        int i1 = (int)rintf(fminf(p1, 127.f));
        int i2 = (int)rintf(fminf(p2, 127.f));
        int i3 = (int)rintf(fminf(p3, 127.f));
        u32 pk = (u32)i0 | ((u32)i1 << 8) | ((u32)i2 << 16) | ((u32)i3 << 24);
#if __has_builtin(__builtin_amdgcn_sdot4)
        lacc = __builtin_amdgcn_sdot4((int)pk, 0x01010101, lacc, false);
#else
        lacc += i0 + i1 + i2 + i3;
#endif
        ((u32*)psb)[((2 * w + (rg >> 1)) * 64 + q) * 4 + 2 * (rg & 1) + hi] = pk;
      }
      if (qf == 0) lsum0 += lacc; else lsum1 += lacc;
    }

    // ---------- preload V kstep 0 of tile it (consumed by PV(it) next iteration)
#pragma unroll
    for (int nd = 0; nd < 3; ++nd)
      vb[0][nd] = Vp[(size_t)(n0 >> 4) * 768 + nd * 16];

    BARRIER_LGKM();   // P(it) visible; kb/vb loads NOT drained
  }

  // ---------- epilogue: PV(15)
  {
    int m0 = 15 * 512;
    i32x4* psp = &Ps[15 & 1][0];
    __builtin_amdgcn_s_setprio(1);
#pragma unroll
    for (int ksv = 0; ksv < 8; ++ksv) {
      int cur = ksv & 1;
      if (ksv < 7) {
#pragma unroll
        for (int nd = 0; nd < 3; ++nd)
          vb[cur ^ 1][nd] = Vp[((size_t)(m0 >> 4) + (ksv + 1) * 4) * 768 + nd * 16];
      }
#pragma unroll
      for (int mq = 0; mq < 4; ++mq) {
        i32x4 pa = psp[(4 * ksv + l4g) * 64 + mq * 16 + l15];
        oacc[mq][0] = __builtin_amdgcn_mfma_i32_16x16x64_i8(pa, vb[cur][0], oacc[mq][0], 0, 0, 0);
        oacc[mq][1] = __builtin_amdgcn_mfma_i32_16x16x64_i8(pa, vb[cur][1], oacc[mq][1], 0, 0, 0);
        oacc[mq][2] = __builtin_amdgcn_mfma_i32_16x16x64_i8(pa, vb[cur][2], oacc[mq][2], 0, 0, 0);
      }
    }
    __builtin_amdgcn_s_setprio(0);
  }

  // ---- l reduction (descale by invps): lanes l, l^32 share q
  {
    float s0 = (float)(lsum0 + __shfl_xor(lsum0, 32)) * invps;
    float s1 = (float)(lsum1 + __shfl_xor(lsum1, 32)) * invps;
    if (hi == 0) { lred[w][ql] = s0; lred[w][ql + 32] = s1; }
  }
  __syncthreads();
  if (t < 64) {
    float s = 0.f;
#pragma unroll
    for (int ww = 0; ww < 16; ++ww) s += lred[ww][t];
    lpart[split * 8192 + qrow0 + t] = s;
  }

  // ---- write unnormalized O partial (bf16); 16x16 C: row=(l>>4)*4+j, col=l&15
#pragma unroll
  for (int mq = 0; mq < 4; ++mq)
#pragma unroll
    for (int nd = 0; nd < 3; ++nd) {
      int col = w * 48 + nd * 16 + l15;
#pragma unroll
      for (int j = 0; j < 4; ++j) {
        int row = qrow0 + mq * 16 + l4g * 4 + j;
        Opart[((size_t)split * 8192 + row) * 768 + col] = f2bf((float)oacc[mq][nd][j] * ovs);
      }
    }
}

// ---------------------------------------------------------------- final combine
__global__ __launch_bounds__(192) void combine(float* __restrict__ out,
                                               const u16* __restrict__ Opart,
                                               const float* __restrict__ lpart,
                                               const float* __restrict__ alpha_p) {
  int row = blockIdx.x, t = threadIdx.x;
  float scale = alpha_p[0] / (lpart[row] + lpart[8192 + row]);
  size_t base = (size_t)row * 768 + t * 4;
  u16x4 o0 = *(const u16x4*)&Opart[base];
  u16x4 o1 = *(const u16x4*)&Opart[(size_t)6291456 + base];
  float4 cur = *(float4*)&out[base];
  union { u32 u; float f; } c0, c1, c2, c3, d0_, d1_, d2_, d3_;
  c0.u = (u32)o0[0] << 16; c1.u = (u32)o0[1] << 16; c2.u = (u32)o0[2] << 16; c3.u = (u32)o0[3] << 16;
  d0_.u = (u32)o1[0] << 16; d1_.u = (u32)o1[1] << 16; d2_.u = (u32)o1[2] << 16; d3_.u = (u32)o1[3] << 16;
  cur.x += (c0.f + d0_.f) * scale;
  cur.y += (c1.f + d1_.f) * scale;
  cur.z += (c2.f + d2_.f) * scale;
  cur.w += (c3.f + d3_.f) * scale;
  *(float4*)&out[base] = cur;
}

// ---------------------------------------------------------------- launch
extern "C" void kernel_launch(void* const* d_in, const int* in_sizes, int n_in,
                              void* d_out, int out_size, void* d_ws, size_t ws_size,
                              hipStream_t stream) {
  const float* x      = (const float*)d_in[0];   // [8192][1024]
  const float* W      = (const float*)d_in[1];   // [768][1024]
  const float* bias   = (const float*)d_in[2];   // [768]
  const float* keys   = (const float*)d_in[3];   // [16384][768]
  const float* values = (const float*)d_in[4];   // [16384][768]
  const float* beta   = (const float*)d_in[5];
  const float* alpha  = (const float*)d_in[6];
  float* out = (float*)d_out;

  char* ws = (char*)d_ws;
  u16* xb    = (u16*)(ws + 0);            // 16,777,216 B
  u16* Wb    = (u16*)(ws + 16777216);     //  1,572,864 B
  u8*  Ki8   = (u8*) (ws + 18350080);     // 12,582,912 B
  u8*  Vi8   = (u8*) (ws + 30932992);     // 12,582,912 B
  u8*  q8    = (u8*) (ws + 43515904);     //  6,291,456 B
  u16* Opart = (u16*)(ws + 49807360);     // 25,165,824 B
  float* lp  = (float*)(ws + 74973184);   //     65,536 B   (total 75,038,720)

  cvt_bf16<<<2048, 256, 0, stream>>>(x, xb, 8192 * 1024 / 4);
  cvt_bf16<<<768, 256, 0, stream>>>(W, Wb, 768 * 1024 / 4);
  buildK<<<256, 256, 0, stream>>>(keys, Ki8);
  buildV<<<256, 256, 0, stream>>>(values, Vi8);
  gemm1<<<dim3(64, 6), 256, 0, stream>>>(xb, Wb, bias, out);
  rownorm8<<<8192, 384, 0, stream>>>(out, q8);
  attn<<<dim3(2, 128), 1024, 0, stream>>>(q8, Ki8, Vi8, beta, Opart, lp);
  combine<<<8192, 192, 0, stream>>>(out, Opart, lp, alpha);
}

// Round 12
// 281.263 us; speedup vs baseline: 1.0755x; 1.0755x over previous
//
#include <hip/hip_runtime.h>
#include <hip/hip_bf16.h>

typedef unsigned char  u8;
typedef unsigned short u16;
typedef unsigned int   u32;
typedef __attribute__((ext_vector_type(8)))  short bf16x8;
typedef __attribute__((ext_vector_type(4)))  float f32x4;
typedef __attribute__((ext_vector_type(4)))  int   i32x4;
typedef __attribute__((ext_vector_type(16))) int   i32x16;
typedef __attribute__((ext_vector_type(4)))  u16   u16x4;

__device__ __forceinline__ u16 f2bf(float f) {
  union { float f; u32 u; } v; v.f = f;
  u32 r = v.u + 0x7FFFu + ((v.u >> 16) & 1u);   // RNE
  return (u16)(r >> 16);
}
__device__ __forceinline__ int q127(float x) { return (int)rintf(x * 127.0f); }

#define GLL16(gptr, lptr)                                                            \
  __builtin_amdgcn_global_load_lds((const __attribute__((address_space(1))) u32*)(gptr), \
                                   (__attribute__((address_space(3))) u32*)(lptr), 16, 0, 0)

// lgkm-only barrier: does NOT drain vmcnt, so global prefetches stay in flight
#define BARRIER_LGKM() do { asm volatile("s_waitcnt lgkmcnt(0)" ::: "memory"); \
                            __builtin_amdgcn_s_barrier(); } while (0)

// ---------------------------------------------------------------- f32 -> bf16
__global__ __launch_bounds__(256) void cvt_bf16(const float* __restrict__ in,
                                                u16* __restrict__ out, int n4) {
  int i = blockIdx.x * blockDim.x + threadIdx.x;
  int stride = gridDim.x * blockDim.x;
  for (; i < n4; i += stride) {
    float4 v = ((const float4*)in)[i];
    u16x4 o = { f2bf(v.x), f2bf(v.y), f2bf(v.z), f2bf(v.w) };
    ((u16x4*)out)[i] = o;
  }
}

// ------------- keys [16384][768] f32 -> Ki8, layout [d16=48][key=16384][16B] i8
__global__ __launch_bounds__(256) void buildK(const float* __restrict__ in,
                                              u8* __restrict__ out) {
  __shared__ float tile[64][65];
  int kt = blockIdx.x;            // 64 keys per block
  int t = threadIdx.x;
  int r0 = t >> 6, c = t & 63;
  for (int dc = 0; dc < 12; ++dc) {
    if (dc) __syncthreads();
#pragma unroll
    for (int i = 0; i < 16; ++i) {
      int r = i * 4 + r0;
      tile[r][c] = in[(size_t)(kt * 64 + r) * 768 + dc * 64 + c];
    }
    __syncthreads();
    int d16l = t >> 6, key = t & 63;   // d16l in 0..3
    u32 wd[4];
#pragma unroll
    for (int g = 0; g < 4; ++g) {
      u32 v = 0;
#pragma unroll
      for (int j = 0; j < 4; ++j)
        v |= (u32)(q127(tile[key][d16l * 16 + g * 4 + j]) & 255) << (8 * j);
      wd[g] = v;
    }
    uint4 val = { wd[0], wd[1], wd[2], wd[3] };
    *(uint4*)(out + ((size_t)(dc * 4 + d16l) * 16384 + (size_t)(kt * 64 + key)) * 16) = val;
  }
}

// ------------- values [16384][768] f32 -> Vi8, layout [k16=1024][d=768][16B] i8
__global__ __launch_bounds__(256) void buildV(const float* __restrict__ in,
                                              u8* __restrict__ out) {
  __shared__ float tile[64][65];
  int kt = blockIdx.x;            // 64 keys per block
  int t = threadIdx.x;
  int r0 = t >> 6, c = t & 63;
  for (int dc = 0; dc < 12; ++dc) {
    if (dc) __syncthreads();
#pragma unroll
    for (int i = 0; i < 16; ++i) {
      int r = i * 4 + r0;
      tile[r][c] = in[(size_t)(kt * 64 + r) * 768 + dc * 64 + c];
    }
    __syncthreads();
    int k16l = t >> 6, dl = t & 63;    // k16l in 0..3
    u32 wd[4];
#pragma unroll
    for (int g = 0; g < 4; ++g) {
      u32 v = 0;
#pragma unroll
      for (int j = 0; j < 4; ++j)
        v |= (u32)(q127(tile[k16l * 16 + g * 4 + j][dl]) & 255) << (8 * j);
      wd[g] = v;
    }
    uint4 val = { wd[0], wd[1], wd[2], wd[3] };
    *(uint4*)(out + ((size_t)(kt * 4 + k16l) * 768 + (size_t)(dc * 64 + dl)) * 16) = val;
  }
}

// ---------------------------------------------------------------- GEMM1 (bf16)
__global__ __launch_bounds__(256) void gemm1(const u16* __restrict__ A,
                                             const u16* __restrict__ B,
                                             const float* __restrict__ bias,
                                             float* __restrict__ C) {
  __shared__ u16 As[2][128 * 32];
  __shared__ u16 Bs[2][128 * 32];
  int t = threadIdx.x;
  int brow = blockIdx.x * 128, bcol = blockIdx.y * 128;
  int w = t >> 6, l = t & 63;
  int l15 = l & 15, l4 = l >> 4;
  int wr = (w >> 1) * 64, wc = (w & 1) * 64;
  f32x4 acc[4][4];
#pragma unroll
  for (int i = 0; i < 4; ++i)
#pragma unroll
    for (int j = 0; j < 4; ++j) acc[i][j] = f32x4{0.f, 0.f, 0.f, 0.f};

  auto stage = [&](int buf, int kt) {
#pragma unroll
    for (int i = 0; i < 2; ++i) {
      int id = t + i * 256;
      int row = id >> 2, c = id & 3;
      int cs = (c ^ (row & 3)) * 8;
      GLL16(A + (size_t)(brow + row) * 1024 + kt * 32 + cs, &As[buf][id * 8]);
      GLL16(B + (size_t)(bcol + row) * 1024 + kt * 32 + cs, &Bs[buf][id * 8]);
    }
  };
  stage(0, 0);
  for (int kt = 0; kt < 32; ++kt) {
    int buf = kt & 1;
    __syncthreads();
    if (kt < 31) stage(buf ^ 1, kt + 1);
    bf16x8 a[4], b[4];
#pragma unroll
    for (int mf = 0; mf < 4; ++mf) {
      int row = wr + mf * 16 + l15;
      a[mf] = *(const bf16x8*)&As[buf][row * 32 + ((l4 ^ (row & 3)) * 8)];
    }
#pragma unroll
    for (int nf = 0; nf < 4; ++nf) {
      int row = wc + nf * 16 + l15;
      b[nf] = *(const bf16x8*)&Bs[buf][row * 32 + ((l4 ^ (row & 3)) * 8)];
    }
#pragma unroll
    for (int mf = 0; mf < 4; ++mf)
#pragma unroll
      for (int nf = 0; nf < 4; ++nf)
        acc[mf][nf] = __builtin_amdgcn_mfma_f32_16x16x32_bf16(a[mf], b[nf], acc[mf][nf], 0, 0, 0);
  }
#pragma unroll
  for (int mf = 0; mf < 4; ++mf)
#pragma unroll
    for (int nf = 0; nf < 4; ++nf) {
      int col = bcol + wc + nf * 16 + l15;
      float bv = bias[col];
#pragma unroll
      for (int j = 0; j < 4; ++j) {
        int row = brow + wr + mf * 16 + l4 * 4 + j;
        C[(size_t)row * 768 + col] = acc[mf][nf][j] + bv;
      }
    }
}

// ---------------------------------------------------------------- row L2-normalize -> i8
__global__ __launch_bounds__(384) void rownorm8(const float* __restrict__ P,
                                                u8* __restrict__ q8) {
  int row = blockIdx.x, t = threadIdx.x;
  size_t base = (size_t)row * 768;
  float2 v = *(const float2*)&P[base + 2 * t];
  float ss = v.x * v.x + v.y * v.y;
#pragma unroll
  for (int o = 32; o; o >>= 1) ss += __shfl_xor(ss, o);
  __shared__ float wsum[6];
  if ((t & 63) == 0) wsum[t >> 6] = ss;
  __syncthreads();
  float tot = wsum[0] + wsum[1] + wsum[2] + wsum[3] + wsum[4] + wsum[5];
  float inv = 1.0f / fmaxf(sqrtf(tot), 1e-12f);
  int a = q127(v.x * inv), b = q127(v.y * inv);
  *(u16*)(q8 + base + 2 * t) = (u16)((a & 255) | ((b & 255) << 8));
}

// ---------------------------------------------------------------- fused attention, i8
// Round-12 = round-10 verbatim (best verified: attn 208.5 us, no spill).
// kb[3], Ps dbuf, one lgkm-only barrier/iter, cross-barrier K prefetch, setprio,
// pscale folded into exp2 arg, lsum via sdot4 on packed P bytes.
__global__ __launch_bounds__(1024, 4) void attn(const u8* __restrict__ q8,
                                                const u8* __restrict__ Ki8,
                                                const u8* __restrict__ Vi8,
                                                const float* __restrict__ beta_p,
                                                u16* __restrict__ Opart,
                                                float* __restrict__ lpart) {
  __shared__ i32x4 Qlds[48 * 64];     // 48 KB [c16][q]
  __shared__ i32x4 Ps[2][32 * 64];    // 2 x 32 KB [kc16][q]
  __shared__ float lred[16][64];      // 4 KB
  int t = threadIdx.x;
  int w = t >> 6, l = t & 63;
  int ql = l & 31, hi = l >> 5;        // 32x32 lanes
  int l15 = l & 15, l4g = l >> 4;      // 16x16 lanes (0..3)
  int split = blockIdx.x, qb = blockIdx.y;
  int qrow0 = qb * 64;
  float beta = beta_p[0];
  float c1 = beta * 1.44269504089f / 16129.0f;          // int logit -> log2 domain
  float lg2ps = 6.98868468677f - beta * 1.44269504089f; // log2(127) - beta*log2(e)
  float invps = expf(beta) / 127.0f;                    // descale for lsum
  float ovs = expf(beta) / 16129.0f;                    // i32 PV acc -> float

  // ---- stage Q [64 q][768 d] i8 into [c16][q] (once)
#pragma unroll
  for (int i = 0; i < 3; ++i) {
    int id = i * 1024 + t;             // id = c16*64 + q
    int c16 = id >> 6, q = id & 63;
    Qlds[id] = *(const i32x4*)(q8 + (size_t)(qrow0 + q) * 768 + (size_t)c16 * 16);
  }

  i32x4 oacc[4][3];
#pragma unroll
  for (int mq = 0; mq < 4; ++mq)
#pragma unroll
    for (int nd = 0; nd < 3; ++nd) oacc[mq][nd] = i32x4{0, 0, 0, 0};
  int lsum0 = 0, lsum1 = 0;

  int kbase = split * 8192;
  const i32x4* Kp = (const i32x4*)Ki8 + (size_t)hi * 16384 + (size_t)(kbase + w * 32 + ql);
  const i32x4* Vp = (const i32x4*)Vi8 + ((size_t)(kbase >> 4) + l4g) * 768 + (size_t)(w * 48 + l15);

  // preload K tile 0 (3-step lookahead, in flight across the staging barrier)
  i32x4 kb[3];
#pragma unroll
  for (int s = 0; s < 3; ++s) kb[s] = Kp[(size_t)(2 * s) * 16384];

  __syncthreads();

  for (int it = 0; it < 16; ++it) {
    int n0 = it * 512;
    const i32x4* kp = Kp + n0;
    i32x4* psb = &Ps[it & 1][0];

    // ---------- QK^T: wave w -> keys [n0+w*32,+32), all 64 q; 24 steps of K=32
    i32x16 sacc0 = (i32x16)0;
    i32x16 sacc1 = (i32x16)0;
    __builtin_amdgcn_s_setprio(1);
#pragma unroll
    for (int ks = 0; ks < 24; ++ks) {
      i32x4 av = kb[ks % 3];
      if (ks < 21) kb[ks % 3] = kp[(size_t)(2 * (ks + 3)) * 16384];
      i32x4 q0 = Qlds[(2 * ks + hi) * 64 + ql];
      i32x4 q1 = Qlds[(2 * ks + hi) * 64 + ql + 32];
      sacc0 = __builtin_amdgcn_mfma_i32_32x32x32_i8(av, q0, sacc0, 0, 0, 0);
      sacc1 = __builtin_amdgcn_mfma_i32_32x32x32_i8(av, q1, sacc1, 0, 0, 0);
    }
    __builtin_amdgcn_s_setprio(0);

    // ---------- exp (pre-scaled), quantize P -> i8 -> Ps[it&1]; lsum via sdot4
    // sacc reg r: key-in-wave = (r&3) + 8*(r>>2) + 4*hi ; q = ql (+32 for sacc1)
#pragma unroll
    for (int qf = 0; qf < 2; ++qf) {
      int q = ql + qf * 32;
      int lacc = 0;
#pragma unroll
      for (int rg = 0; rg < 4; ++rg) {
        float p0, p1, p2, p3;
        if (qf == 0) {
          p0 = exp2f(fmaf(c1, (float)sacc0[rg * 4 + 0], lg2ps));
          p1 = exp2f(fmaf(c1, (float)sacc0[rg * 4 + 1], lg2ps));
          p2 = exp2f(fmaf(c1, (float)sacc0[rg * 4 + 2], lg2ps));
          p3 = exp2f(fmaf(c1, (float)sacc0[rg * 4 + 3], lg2ps));
        } else {
          p0 = exp2f(fmaf(c1, (float)sacc1[rg * 4 + 0], lg2ps));
          p1 = exp2f(fmaf(c1, (float)sacc1[rg * 4 + 1], lg2ps));
          p2 = exp2f(fmaf(c1, (float)sacc1[rg * 4 + 2], lg2ps));
          p3 = exp2f(fmaf(c1, (float)sacc1[rg * 4 + 3], lg2ps));
        }
        int i0 = (int)rintf(fminf(p0, 127.f));
        int i1 = (int)rintf(fminf(p1, 127.f));
        int i2 = (int)rintf(fminf(p2, 127.f));
        int i3 = (int)rintf(fminf(p3, 127.f));
        u32 pk = (u32)i0 | ((u32)i1 << 8) | ((u32)i2 << 16) | ((u32)i3 << 24);
#if __has_builtin(__builtin_amdgcn_sdot4)
        lacc = __builtin_amdgcn_sdot4((int)pk, 0x01010101, lacc, false);
#else
        lacc += i0 + i1 + i2 + i3;
#endif
        ((u32*)psb)[((2 * w + (rg >> 1)) * 64 + q) * 4 + 2 * (rg & 1) + hi] = pk;
      }
      if (qf == 0) lsum0 += lacc; else lsum1 += lacc;
    }

    // ---------- prefetch K for next tile (stays in flight across barrier)
    if (it < 15) {
      const i32x4* kpn = Kp + (size_t)(it + 1) * 512;
#pragma unroll
      for (int s = 0; s < 3; ++s) kb[s] = kpn[(size_t)(2 * s) * 16384];
    }
    // ---------- preload V for kstep 0 (no Ps dependency -> before barrier)
    i32x4 vb[2][3];
#pragma unroll
    for (int nd = 0; nd < 3; ++nd)
      vb[0][nd] = Vp[(size_t)(n0 >> 4) * 768 + nd * 16];

    BARRIER_LGKM();   // P(it) visible; kb/vb loads NOT drained

    // ---------- PV: O[64 q][48 d per wave] += P * V  (16x16x64 i8, 8 ksteps)
    __builtin_amdgcn_s_setprio(1);
#pragma unroll
    for (int ksv = 0; ksv < 8; ++ksv) {
      int cur = ksv & 1;
      if (ksv < 7) {
#pragma unroll
        for (int nd = 0; nd < 3; ++nd)
          vb[cur ^ 1][nd] = Vp[((size_t)(n0 >> 4) + (ksv + 1) * 4) * 768 + nd * 16];
      }
#pragma unroll
      for (int mq = 0; mq < 4; ++mq) {
        i32x4 pa = psb[(4 * ksv + l4g) * 64 + mq * 16 + l15];
        oacc[mq][0] = __builtin_amdgcn_mfma_i32_16x16x64_i8(pa, vb[cur][0], oacc[mq][0], 0, 0, 0);
        oacc[mq][1] = __builtin_amdgcn_mfma_i32_16x16x64_i8(pa, vb[cur][1], oacc[mq][1], 0, 0, 0);
        oacc[mq][2] = __builtin_amdgcn_mfma_i32_16x16x64_i8(pa, vb[cur][2], oacc[mq][2], 0, 0, 0);
      }
    }
    __builtin_amdgcn_s_setprio(0);
    // no second barrier: Ps double-buffered; rewrite of Ps[it&1] is after the NEXT barrier
  }

  // ---- l reduction (descale by invps): lanes l, l^32 share q
  {
    float s0 = (float)(lsum0 + __shfl_xor(lsum0, 32)) * invps;
    float s1 = (float)(lsum1 + __shfl_xor(lsum1, 32)) * invps;
    if (hi == 0) { lred[w][ql] = s0; lred[w][ql + 32] = s1; }
  }
  __syncthreads();
  if (t < 64) {
    float s = 0.f;
#pragma unroll
    for (int ww = 0; ww < 16; ++ww) s += lred[ww][t];
    lpart[split * 8192 + qrow0 + t] = s;
  }

  // ---- write unnormalized O partial (bf16); 16x16 C: row=(l>>4)*4+j, col=l&15
#pragma unroll
  for (int mq = 0; mq < 4; ++mq)
#pragma unroll
    for (int nd = 0; nd < 3; ++nd) {
      int col = w * 48 + nd * 16 + l15;
#pragma unroll
      for (int j = 0; j < 4; ++j) {
        int row = qrow0 + mq * 16 + l4g * 4 + j;
        Opart[((size_t)split * 8192 + row) * 768 + col] = f2bf((float)oacc[mq][nd][j] * ovs);
      }
    }
}

// ---------------------------------------------------------------- final combine
__global__ __launch_bounds__(192) void combine(float* __restrict__ out,
                                               const u16* __restrict__ Opart,
                                               const float* __restrict__ lpart,
                                               const float* __restrict__ alpha_p) {
  int row = blockIdx.x, t = threadIdx.x;
  float scale = alpha_p[0] / (lpart[row] + lpart[8192 + row]);
  size_t base = (size_t)row * 768 + t * 4;
  u16x4 o0 = *(const u16x4*)&Opart[base];
  u16x4 o1 = *(const u16x4*)&Opart[(size_t)6291456 + base];
  float4 cur = *(float4*)&out[base];
  union { u32 u; float f; } c0, c1, c2, c3, d0_, d1_, d2_, d3_;
  c0.u = (u32)o0[0] << 16; c1.u = (u32)o0[1] << 16; c2.u = (u32)o0[2] << 16; c3.u = (u32)o0[3] << 16;
  d0_.u = (u32)o1[0] << 16; d1_.u = (u32)o1[1] << 16; d2_.u = (u32)o1[2] << 16; d3_.u = (u32)o1[3] << 16;
  cur.x += (c0.f + d0_.f) * scale;
  cur.y += (c1.f + d1_.f) * scale;
  cur.z += (c2.f + d2_.f) * scale;
  cur.w += (c3.f + d3_.f) * scale;
  *(float4*)&out[base] = cur;
}

// ---------------------------------------------------------------- launch
extern "C" void kernel_launch(void* const* d_in, const int* in_sizes, int n_in,
                              void* d_out, int out_size, void* d_ws, size_t ws_size,
                              hipStream_t stream) {
  const float* x      = (const float*)d_in[0];   // [8192][1024]
  const float* W      = (const float*)d_in[1];   // [768][1024]
  const float* bias   = (const float*)d_in[2];   // [768]
  const float* keys   = (const float*)d_in[3];   // [16384][768]
  const float* values = (const float*)d_in[4];   // [16384][768]
  const float* beta   = (const float*)d_in[5];
  const float* alpha  = (const float*)d_in[6];
  float* out = (float*)d_out;

  char* ws = (char*)d_ws;
  u16* xb    = (u16*)(ws + 0);            // 16,777,216 B
  u16* Wb    = (u16*)(ws + 16777216);     //  1,572,864 B
  u8*  Ki8   = (u8*) (ws + 18350080);     // 12,582,912 B
  u8*  Vi8   = (u8*) (ws + 30932992);     // 12,582,912 B
  u8*  q8    = (u8*) (ws + 43515904);     //  6,291,456 B
  u16* Opart = (u16*)(ws + 49807360);     // 25,165,824 B
  float* lp  = (float*)(ws + 74973184);   //     65,536 B   (total 75,038,720)

  cvt_bf16<<<2048, 256, 0, stream>>>(x, xb, 8192 * 1024 / 4);
  cvt_bf16<<<768, 256, 0, stream>>>(W, Wb, 768 * 1024 / 4);
  buildK<<<256, 256, 0, stream>>>(keys, Ki8);
  buildV<<<256, 256, 0, stream>>>(values, Vi8);
  gemm1<<<dim3(64, 6), 256, 0, stream>>>(xb, Wb, bias, out);
  rownorm8<<<8192, 384, 0, stream>>>(out, q8);
  attn<<<dim3(2, 128), 1024, 0, stream>>>(q8, Ki8, Vi8, beta, Opart, lp);
  combine<<<8192, 192, 0, stream>>>(out, Opart, lp, alpha);
}